// Round 3
// baseline (55437.579 us; speedup 1.0000x reference)
//
#include <hip/hip_runtime.h>
#include <cstdio>
#include <cstdint>
#include <cstddef>

// FPLSTM: T=8192 steps, IN=2048, M=2048.
//  Kernel 1: init  (zero replicated h/a line arrays)
//  Kernel 2: gemm  xg[t,n] = inputs[t,:]·Wx[n,:] + bx[n], stored bf16
//  Kernel 3: persistent cooperative recurrence, 256 blocks x 512 thr.
//
// R6 = R5 structure with the poll reverted to R4's single-asm-block
// load (R5's depth-2 pipelined poll leaked in-flight load registers
// across asm-block boundaries -> regalloc hazard -> read wrong lines
// with valid epoch bits -> absmax 5.7e-2 fail).
//
// Structure (from R5):
//  - z-fast-path: a = z*tanh(c) needs only the z gate (Wh rows 2M..3M),
//    computed by waves 2 (half0) and 6 (half1). Wave6 passes its sums
//    via LDS + monotonic flag; wave2 publishes a WITHOUT the block
//    barrier or a wave0 gather hop. i/o/f gates are computed per-wave
//    (wave w owns element w) during the phase-B poll window.
//  - phase B: wave w computes the full Wm row (8b+w) (32 FMA/lane),
//    full-wave butterfly, then the scalar u/c/h chain and publishes its
//    dword to all 8 copies directly. No redM, no second barrier, no
//    wave0 serialization. hs double-buffered (hsA/hsB) so no barrier is
//    needed between h-publish and the next phase-A poll/stage.
//  3 barriers/step (A-stage, redL, B-stage), none on a publish path.
//
// Epoch scheme (R4): every published dword carries epoch in its low 2
// mantissa bits (error <= 4e-7 rel). h line epoch (2t+2)&3 at end of
// step t; a line epoch (2t+1)&3 in phase B of step t. Lap argument: a
// writer's next publish transitively requires all blocks' prior-phase
// publishes, which require consumption -> staleness bounded to one
// epoch; adjacent epochs of a line differ by 2 mod 4 (no alias).
// Init zeros = epoch 0 = the t=0 h.

#define T_STEPS 8192
#define MEM     2048
#define NG5     10240   // 5*MEM
#define NBLK    256
#define NTHR    512
#define RCOPY   8

// line = 16 dwords: f[0..7] = dwords 0..7, pad 8..15 (64B stride kept)
static constexpr size_t XG_BYTES  = (size_t)T_STEPS * NG5 * 2;     // bf16 xg
static constexpr size_t HREP_OFF  = XG_BYTES;                       // 8*256*64 B
static constexpr size_t REP_BYTES = (size_t)RCOPY * NBLK * 64;
static constexpr size_t AREP_OFF  = HREP_OFF + REP_BYTES;
static constexpr size_t WS_NEEDED = AREP_OFF + REP_BYTES;

__device__ __forceinline__ float bf2f(unsigned short u) {
  return __uint_as_float(((unsigned int)u) << 16);
}
__device__ __forceinline__ unsigned short f2bf(float f) {
  unsigned int u = __float_as_uint(f);
  u += 0x7FFFu + ((u >> 16) & 1u);   // RNE; inputs finite
  return (unsigned short)(u >> 16);
}
__device__ __forceinline__ float sigmoidf_(float x) {
  return 1.0f / (1.0f + __expf(-x));
}
__device__ __forceinline__ float tanhf_(float x) {
  x = fminf(fmaxf(x, -15.0f), 15.0f);
  float e = __expf(2.0f * x);
  return (e - 1.0f) / (e + 1.0f);
}

// ---- per-access coherent ops (bypass L1+L2; coherence point = L3) ----
__device__ __forceinline__ void store_i_cc(int* p, int v) {
  asm volatile("global_store_dword %0, %1, off sc0 sc1"
               :: "v"(p), "v"(v) : "memory");
}
// single-block load+wait: no in-flight state escapes the asm block.
__device__ __forceinline__ int4 load4_cc(const float* p) {
  int4 v;
  asm volatile("global_load_dwordx4 %0, %1, off sc0 sc1\n\t"
               "s_waitcnt vmcnt(0)"
               : "=v"(v) : "v"(p) : "memory");
  return v;
}
__device__ __forceinline__ bool quad_ok(const int4 v, const int e2) {
  return ((((v.x ^ e2) | (v.y ^ e2) | (v.z ^ e2) | (v.w ^ e2)) & 3) == 0);
}
__device__ __forceinline__ int4 poll_quad(const float* p, const int e2) {
  for (;;) {
    int4 v = load4_cc(p);
    if (__all(quad_ok(v, e2))) return v;
  }
}

// ---------------------------------------------------------------- init
__global__ void fplstm_init(int* rep) {   // zero hrep+arep (epoch 0 = t=0 h)
  const int tid = threadIdx.x;
  const int n = 2 * RCOPY * NBLK * 16;
  for (int i = tid; i < n; i += 256) rep[i] = 0;
}

// ---------------------------------------------------------------- GEMM
// C(8192x10240) = A(8192x2048) @ W(10240x2048)^T + bx ; write bf16.
__global__ __launch_bounds__(256, 2) void fplstm_gemm(
    const float* __restrict__ A, const float* __restrict__ W,
    const float* __restrict__ bx, unsigned short* __restrict__ xg)
{
  __shared__ float As[16][132];
  __shared__ float Bs[16][144];
  const int tid = threadIdx.x;
  const int bn = blockIdx.x;      // 80 N-tiles
  const int bm = blockIdx.y;      // 64 M-tiles
  const int tx = tid & 15, ty = tid >> 4;
  const int lrow = tid >> 1;
  const int kh   = (tid & 1) * 8;
  const float* Ap = A + (size_t)(bm * 128 + lrow) * 2048 + kh;
  const float* Wp = W + (size_t)(bn * 128 + lrow) * 2048 + kh;
  const int bmap = lrow + 4 * (lrow >> 5);
  const int bb   = 8 * tx + 4 * (tx >> 2);

  float acc[8][8];
#pragma unroll
  for (int i = 0; i < 8; ++i)
#pragma unroll
    for (int j = 0; j < 8; ++j) acc[i][j] = 0.0f;

  for (int k0 = 0; k0 < 2048; k0 += 16) {
    float4 a0 = *(const float4*)(Ap + k0);
    float4 a1 = *(const float4*)(Ap + k0 + 4);
    float4 b0 = *(const float4*)(Wp + k0);
    float4 b1 = *(const float4*)(Wp + k0 + 4);
    __syncthreads();
    As[kh+0][lrow] = a0.x; As[kh+1][lrow] = a0.y; As[kh+2][lrow] = a0.z; As[kh+3][lrow] = a0.w;
    As[kh+4][lrow] = a1.x; As[kh+5][lrow] = a1.y; As[kh+6][lrow] = a1.z; As[kh+7][lrow] = a1.w;
    Bs[kh+0][bmap] = b0.x; Bs[kh+1][bmap] = b0.y; Bs[kh+2][bmap] = b0.z; Bs[kh+3][bmap] = b0.w;
    Bs[kh+4][bmap] = b1.x; Bs[kh+5][bmap] = b1.y; Bs[kh+6][bmap] = b1.z; Bs[kh+7][bmap] = b1.w;
    __syncthreads();
#pragma unroll
    for (int k = 0; k < 16; ++k) {
      float4 x0 = *(const float4*)(&As[k][8 * ty]);
      float4 x1 = *(const float4*)(&As[k][8 * ty + 4]);
      float4 y0 = *(const float4*)(&Bs[k][bb]);
      float4 y1 = *(const float4*)(&Bs[k][bb + 4]);
      float xa[8] = {x0.x, x0.y, x0.z, x0.w, x1.x, x1.y, x1.z, x1.w};
      float yb[8] = {y0.x, y0.y, y0.z, y0.w, y1.x, y1.y, y1.z, y1.w};
#pragma unroll
      for (int i = 0; i < 8; ++i)
#pragma unroll
        for (int j = 0; j < 8; ++j)
          acc[i][j] = fmaf(xa[i], yb[j], acc[i][j]);
    }
  }

  float bxa[8];
  {
    float4 q0 = *(const float4*)(bx + bn * 128 + 8 * tx);
    float4 q1 = *(const float4*)(bx + bn * 128 + 8 * tx + 4);
    bxa[0]=q0.x; bxa[1]=q0.y; bxa[2]=q0.z; bxa[3]=q0.w;
    bxa[4]=q1.x; bxa[5]=q1.y; bxa[6]=q1.z; bxa[7]=q1.w;
  }
#pragma unroll
  for (int i = 0; i < 8; ++i) {
    const size_t row = (size_t)(bm * 128 + 8 * ty + i);
    unsigned short t8[8];
#pragma unroll
    for (int j = 0; j < 8; ++j) t8[j] = f2bf(acc[i][j] + bxa[j]);
    unsigned short* p = xg + row * NG5 + bn * 128 + 8 * tx;
    *(ushort4*)(p)     = make_ushort4(t8[0], t8[1], t8[2], t8[3]);
    *(ushort4*)(p + 4) = make_ushort4(t8[4], t8[5], t8[6], t8[7]);
  }
}

// ---------------------------------------------------------------- recurrence
// Block b owns elements [8b,8b+8). Wave w: Wh gate rg=w&3, half hf=w>>2;
// element owner for gates/c/h/Wm-row = element w.
__global__ __launch_bounds__(NTHR, 2) void fplstm_recur(
    const unsigned short* __restrict__ xg,
    float* hrep, float* arep,
    const float* __restrict__ Wh, const float* __restrict__ bh,
    const float* __restrict__ Wm, const float* __restrict__ bm,
    float* __restrict__ out)
{
  const int tid  = threadIdx.x;
  const int b    = blockIdx.x;
  const int w    = tid >> 6;
  const int lane = tid & 63;
  const int rg   = w & 3;
  const int hf   = w >> 2;
  const int colbase = 1024 * hf + 4 * lane;
  const int j7   = lane & 7;
  // bit-reverse-3 (involution): row index held by this lane after the
  // reduce-scatter butterfly, and the shfl source for re-permutation.
  const int rperm = ((j7 & 1) << 2) | (j7 & 2) | ((j7 >> 2) & 1);

  // ---- one-time: weights -> registers ----
  float whr[8][16];                     // Wh gate rg rows 8b..8b+8, half hf
#pragma unroll
  for (int r = 0; r < 8; ++r) {
    const float* wp = Wh + (size_t)(rg * MEM + 8 * b + r) * MEM + colbase;
#pragma unroll
    for (int k = 0; k < 4; ++k) {
      float4 v = *(const float4*)(wp + 256 * k);
      whr[r][4*k+0] = v.x; whr[r][4*k+1] = v.y; whr[r][4*k+2] = v.z; whr[r][4*k+3] = v.w;
    }
  }
  float wm32[32];                       // Wm full row (8b+w), cols 4*lane+256k
  {
    const float* wp = Wm + (size_t)(8 * b + w) * MEM + 4 * lane;
#pragma unroll
    for (int k = 0; k < 8; ++k) {
      float4 v = *(const float4*)(wp + 256 * k);
      wm32[4*k+0] = v.x; wm32[4*k+1] = v.y; wm32[4*k+2] = v.z; wm32[4*k+3] = v.w;
    }
  }
  // per-wave biases (element w); all lanes redundant (broadcast loads)
  const float bhi = bh[0 * MEM + 8 * b + w];
  const float bho = bh[1 * MEM + 8 * b + w];
  const float bhf = bh[3 * MEM + 8 * b + w];
  const float bmw = bm[8 * b + w];
  const float bhz = bh[2 * MEM + 8 * b + rperm];   // z bias, permuted layout

  __shared__ float hsA[MEM];        // staged h (phase A)
  __shared__ float hsB[MEM];        // staged a (phase B)
  __shared__ float redL[8][8];      // Wh partial row-sums [wave][row]
  __shared__ float tcL[8];          // tanh(c) per element
  __shared__ int   zflag;           // wave6 -> wave2 handoff (monotonic)

  if (tid == 0) zflag = 0;
  if (tid < 8) tcL[tid] = 0.0f;     // ordered before use by BARRIER-A(t=0)

  // collector addressing: wave w covers lines [32w,32w+32) of copy b&7;
  // lane covers line = 32w + (lane>>1), half = lane&1 (16B of 32B data).
  const int copy  = b & 7;
  const int line  = 32 * w + (lane >> 1);
  const int half  = lane & 1;
  const float* hl = hrep + (size_t)(copy * NBLK + line) * 16 + 4 * half;
  const float* al = arep + (size_t)(copy * NBLK + line) * 16 + 4 * half;

  // publisher addressing:
  //  a (wave2, 64 lanes): copy lane>>3, elem lane&7
  //  h (each wave, lanes<8): copy lane, dword w
  int* a_pub = (int*)arep + ((size_t)((lane >> 3) * NBLK + b) * 16 + j7);
  int* h_pub = (int*)hrep + ((size_t)(lane * NBLK + b) * 16 + w);

  float c_w = 0.0f, h_keep = 0.0f;

  for (int t = 0; t < T_STEPS; ++t) {
    // prefetch xg row t for element w (plain cached loads; tiny)
    const unsigned short* xrow = xg + (size_t)t * NG5 + 8 * b;
    const float xvi = bf2f(xrow[0 * MEM + w]);
    const float xvo = bf2f(xrow[1 * MEM + w]);
    const float xvf = bf2f(xrow[3 * MEM + w]);
    const float xvu = bf2f(xrow[4 * MEM + w]);
    float xvz = 0.0f;
    if (w == 2) xvz = bf2f(xrow[2 * MEM + rperm]);

    // ---- phase A: poll h lines (low2 == (2t)&3), stage to hsA ----
    {
      int4 v = poll_quad(hl, (2 * t) & 3);
      *(int4*)&hsA[8 * line + 4 * half] = v;
    }
    __syncthreads();                                   // BARRIER-A

    // ---- Wh partials (gate rg, half hf) ----
    float hreg[16];
#pragma unroll
    for (int k = 0; k < 4; ++k) {
      float4 v = *(const float4*)&hsA[colbase + 256 * k];
      hreg[4*k+0] = v.x; hreg[4*k+1] = v.y; hreg[4*k+2] = v.z; hreg[4*k+3] = v.w;
    }
    float acc[8];
#pragma unroll
    for (int r = 0; r < 8; ++r) {
      float s = 0.0f;
#pragma unroll
      for (int j = 0; j < 16; ++j) s = fmaf(whr[r][j], hreg[j], s);
      acc[r] = s;
    }
    // butterfly reduce-scatter: all lanes end with row rperm's total
    float v4[4];
    {
      const int b0 = lane & 1;
#pragma unroll
      for (int i = 0; i < 4; ++i) {
        float sent = b0 ? acc[i] : acc[4 + i];
        float got  = __shfl_xor(sent, 1, 64);
        v4[i] = (b0 ? acc[4 + i] : acc[i]) + got;
      }
    }
    float v2[2];
    {
      const int b1 = (lane >> 1) & 1;
#pragma unroll
      for (int i = 0; i < 2; ++i) {
        float sent = b1 ? v4[i] : v4[2 + i];
        float got  = __shfl_xor(sent, 2, 64);
        v2[i] = (b1 ? v4[2 + i] : v4[i]) + got;
      }
    }
    float v1r;
    {
      const int b2 = (lane >> 2) & 1;
      float sent = b2 ? v2[0] : v2[1];
      float got  = __shfl_xor(sent, 4, 64);
      v1r = (b2 ? v2[1] : v2[0]) + got;
    }
    v1r += __shfl_xor(v1r, 8, 64);
    v1r += __shfl_xor(v1r, 16, 64);
    v1r += __shfl_xor(v1r, 32, 64);

    if (w == 2) {
      // ---- z-fast-path: combine with wave6's half, publish a ----
      while (*(volatile int*)&zflag < t + 1) { }
      __threadfence_block();
      const float zh = v1r + redL[6][rperm];
      const float z  = sigmoidf_(xvz + zh + bhz);
      const float ap = z * tcL[rperm];         // a for elem rperm (permuted)
      const float av = __shfl(ap, rperm, 64);  // a for elem lane&7 everywhere
      store_i_cc(a_pub, (__float_as_int(av) & ~3) | (int)((2 * t + 1) & 3));
    } else {
      if (lane < 8) redL[w][rperm] = v1r;
      if (w == 6) {
        __threadfence_block();                 // redL[6] visible first
        if (lane == 0) *(volatile int*)&zflag = t + 1;
      }
    }
    __syncthreads();                                   // BARRIER-G

    // ---- gates for element w (overlaps phase-B communication) ----
    const float gi = sigmoidf_(xvi + redL[0][w] + redL[4][w] + bhi);
    const float go = sigmoidf_(xvo + redL[1][w] + redL[5][w] + bho);
    const float gf = sigmoidf_(xvf + redL[3][w] + redL[7][w] + bhf);
    const float fc = gf * c_w;

    // ---- phase B: poll a lines (low2 == (2t+1)&3), stage to hsB ----
    {
      int4 v = poll_quad(al, (2 * t + 1) & 3);
      *(int4*)&hsB[8 * line + 4 * half] = v;
    }
    __syncthreads();                                   // BARRIER-B

    // ---- Wm full row (8b+w): 32 FMA/lane + full-wave butterfly ----
    float s0 = 0.0f, s1 = 0.0f, s2 = 0.0f, s3 = 0.0f;
#pragma unroll
    for (int k = 0; k < 8; ++k) {
      float4 q = *(const float4*)&hsB[4 * lane + 256 * k];
      s0 = fmaf(wm32[4*k+0], q.x, s0);
      s1 = fmaf(wm32[4*k+1], q.y, s1);
      s2 = fmaf(wm32[4*k+2], q.z, s2);
      s3 = fmaf(wm32[4*k+3], q.w, s3);
    }
    float mg = (s0 + s1) + (s2 + s3);
    mg += __shfl_xor(mg, 1, 64);
    mg += __shfl_xor(mg, 2, 64);
    mg += __shfl_xor(mg, 4, 64);
    mg += __shfl_xor(mg, 8, 64);
    mg += __shfl_xor(mg, 16, 64);
    mg += __shfl_xor(mg, 32, 64);

    // ---- scalar chain for element w (all lanes redundant) ----
    const float uu  = tanhf_(xvu + mg + bmw);
    const float cn  = fmaf(gi, uu, fc);
    const float tch = tanhf_(cn);
    const float hv  = go * tch;
    c_w = cn;
    if (lane == 0) tcL[w] = tch;               // for next step's z-fast-path
    if (lane < 8)
      store_i_cc(h_pub, (__float_as_int(hv) & ~3) | (int)((2 * t + 2) & 3));
    h_keep = hv;
    // next phase-A poll (epoch (2t+2)&3) is the cross-block barrier;
    // hsA/hsB double-buffering makes an end-of-step barrier unnecessary.
  }

  if (lane == 0) out[8 * b + w] = h_keep;
}

// ---------------------------------------------------------------- launch
extern "C" void kernel_launch(void* const* d_in, const int* in_sizes, int n_in,
                              void* d_out, int out_size, void* d_ws, size_t ws_size,
                              hipStream_t stream) {
  const float* inputs = (const float*)d_in[0];
  const float* Wx     = (const float*)d_in[1];
  const float* bx     = (const float*)d_in[2];
  const float* Wh     = (const float*)d_in[3];
  const float* bh     = (const float*)d_in[4];
  const float* Wm     = (const float*)d_in[5];
  const float* bm     = (const float*)d_in[6];
  float* out = (float*)d_out;
  char* ws = (char*)d_ws;

  if (ws_size < WS_NEEDED) {
    fprintf(stderr, "FPLSTM: ws_size %zu < needed %zu -- cannot run\n",
            ws_size, (size_t)WS_NEEDED);
    return;
  }

  unsigned short* xg = (unsigned short*)ws;
  float* hrep = (float*)(ws + HREP_OFF);
  float* arep = (float*)(ws + AREP_OFF);

  fplstm_init<<<1, 256, 0, stream>>>((int*)hrep);
  fplstm_gemm<<<dim3(80, 64), 256, 0, stream>>>(inputs, Wx, bx, xg);

  void* args[] = {(void*)&xg, (void*)&hrep, (void*)&arep,
                  (void*)&Wh, (void*)&bh, (void*)&Wm, (void*)&bm, (void*)&out};
  hipError_t e = hipLaunchCooperativeKernel((void*)fplstm_recur, dim3(NBLK),
                                            dim3(NTHR), args, 0, stream);
  if (e != hipSuccess) {
    fprintf(stderr, "FPLSTM: coop launch failed (%d), plain launch\n", (int)e);
    fplstm_recur<<<dim3(NBLK), dim3(NTHR), 0, stream>>>(
        xg, hrep, arep, Wh, bh, Wm, bm, out);
  }
}

// Round 6
// 49060.223 us; speedup vs baseline: 1.1300x; 1.1300x over previous
//
#include <hip/hip_runtime.h>
#include <cstdio>
#include <cstdint>
#include <cstddef>

// FPLSTM: T=8192 steps, IN=2048, M=2048.
//  Kernel 1: init  (zero replicated h/a line arrays)
//  Kernel 2: gemm  xg[t,n] = inputs[t,:]·Wx[n,:] + bx[n], stored bf16 PACKED
//            per-block: xg[t][blk][gate][8] so one block's 40 ushorts/step
//            sit in <=2 cache lines (was 5 lines across 10KB).
//  Kernel 3: persistent cooperative recurrence, 256 blocks x 512 thr.
//
// R9: depth-2 poll moved ENTIRELY into one asm block with hard-pinned
// registers (slots v[48:51]/v[52:55], temps v56/v57, all clobbered).
// R5/R8 kept in-flight load destinations visible to the compiler across
// asm-block boundaries; "=&v" + keep-alives + sched_barrier close the
// scheduler/aliasing holes but NOT regalloc live-range splits (a copy
// of an in-flight slot reads its registers before the data lands).
// R8's rare-corruption absmax 1.72e-2 is that class. With the whole
// loop in one asm, no in-flight state ever crosses a compiler boundary
// -- same soundness argument as R4's proven single-slot poll, at
// sampling period tau/2 instead of tau.
//   loop: vmcnt(1) -> older slot landed -> epoch-check in asm
//         (v_xor/v_or/v_and, v_cmp_ne vcc, s_cbranch_vccz);
//         hit -> vmcnt(0) drain, v_mov to outputs; miss -> reissue slot.
//
// Epoch scheme (R4): every published dword carries epoch in its low 2
// mantissa bits (error <= 4e-7 rel). h line epoch (2t+2)&3 at end of
// step t; a line epoch (2t+1)&3 in phase B of step t. Lap argument: a
// writer's next publish transitively requires all blocks' prior-phase
// publishes, which require consumption -> staleness bounded to one
// epoch; adjacent epochs of a line differ by 2 mod 4 (no alias).
// Init zeros = epoch 0 = the t=0 h.

#define T_STEPS 8192
#define MEM     2048
#define NG5     10240   // 5*MEM
#define NBLK    256
#define NTHR    512
#define RCOPY   8

// line = 16 dwords: f[0..7] = dwords 0..7, pad 8..15 (64B stride kept)
static constexpr size_t XG_BYTES  = (size_t)T_STEPS * NG5 * 2;     // bf16 xg
static constexpr size_t HREP_OFF  = XG_BYTES;                       // 8*256*64 B
static constexpr size_t REP_BYTES = (size_t)RCOPY * NBLK * 64;
static constexpr size_t AREP_OFF  = HREP_OFF + REP_BYTES;
static constexpr size_t WS_NEEDED = AREP_OFF + REP_BYTES;

__device__ __forceinline__ float bf2f(unsigned short u) {
  return __uint_as_float(((unsigned int)u) << 16);
}
__device__ __forceinline__ unsigned short f2bf(float f) {
  unsigned int u = __float_as_uint(f);
  u += 0x7FFFu + ((u >> 16) & 1u);   // RNE; inputs finite
  return (unsigned short)(u >> 16);
}
__device__ __forceinline__ float sigmoidf_(float x) {
  return 1.0f / (1.0f + __expf(-x));
}
__device__ __forceinline__ float tanhf_(float x) {
  x = fminf(fmaxf(x, -15.0f), 15.0f);
  float e = __expf(2.0f * x);
  return (e - 1.0f) / (e + 1.0f);
}

// ---- per-access coherent ops (bypass L1+L2; coherence point = L3) ----
__device__ __forceinline__ void store_i_cc(int* p, int v) {
  asm volatile("global_store_dword %0, %1, off sc0 sc1"
               :: "v"(p), "v"(v) : "memory");
}

// depth-2 pipelined poll, fully inside ONE asm block. Slots pinned to
// v[48:51]/v[52:55]; temps v56/v57; all clobbered. vmcnt retires in
// issue order, so vmcnt(1) at the loop head always means "the older
// poll slot landed" (pre-existing outstanding prefetch/publish ops just
// get drained by the first wait). All 64 lanes participate (no
// divergence at call sites), so vccz == "every lane's quad is valid".
__device__ __forceinline__ int4 poll_quad(const float* p, const int e2) {
  int r0, r1, r2, r3;
  asm volatile(
    "global_load_dwordx4 v[48:51], %[p], off sc0 sc1\n\t"
    "global_load_dwordx4 v[52:55], %[p], off sc0 sc1\n\t"
    "PL%=:\n\t"
    "s_waitcnt vmcnt(1)\n\t"               // slot A landed
    "v_xor_b32 v56, %[e2], v48\n\t"
    "v_xor_b32 v57, %[e2], v49\n\t"
    "v_or_b32 v56, v56, v57\n\t"
    "v_xor_b32 v57, %[e2], v50\n\t"
    "v_or_b32 v56, v56, v57\n\t"
    "v_xor_b32 v57, %[e2], v51\n\t"
    "v_or_b32 v56, v56, v57\n\t"
    "v_and_b32 v56, 3, v56\n\t"
    "v_cmp_ne_u32 vcc, 0, v56\n\t"         // lanes whose A-quad is invalid
    "s_cbranch_vccz GA%=\n\t"
    "global_load_dwordx4 v[48:51], %[p], off sc0 sc1\n\t"
    "s_waitcnt vmcnt(1)\n\t"               // slot B landed
    "v_xor_b32 v56, %[e2], v52\n\t"
    "v_xor_b32 v57, %[e2], v53\n\t"
    "v_or_b32 v56, v56, v57\n\t"
    "v_xor_b32 v57, %[e2], v54\n\t"
    "v_or_b32 v56, v56, v57\n\t"
    "v_xor_b32 v57, %[e2], v55\n\t"
    "v_or_b32 v56, v56, v57\n\t"
    "v_and_b32 v56, 3, v56\n\t"
    "v_cmp_ne_u32 vcc, 0, v56\n\t"
    "s_cbranch_vccz GB%=\n\t"
    "global_load_dwordx4 v[52:55], %[p], off sc0 sc1\n\t"
    "s_branch PL%=\n\t"
    "GB%=:\n\t"
    "s_waitcnt vmcnt(0)\n\t"               // drain in-flight A reissue
    "v_mov_b32 %[r0], v52\n\t"
    "v_mov_b32 %[r1], v53\n\t"
    "v_mov_b32 %[r2], v54\n\t"
    "v_mov_b32 %[r3], v55\n\t"
    "s_branch DN%=\n\t"
    "GA%=:\n\t"
    "s_waitcnt vmcnt(0)\n\t"               // drain in-flight B slot
    "v_mov_b32 %[r0], v48\n\t"
    "v_mov_b32 %[r1], v49\n\t"
    "v_mov_b32 %[r2], v50\n\t"
    "v_mov_b32 %[r3], v51\n\t"
    "DN%=:"
    : [r0]"=&v"(r0), [r1]"=&v"(r1), [r2]"=&v"(r2), [r3]"=&v"(r3)
    : [p]"v"(p), [e2]"s"(e2)
    : "memory", "vcc",
      "v48","v49","v50","v51","v52","v53","v54","v55","v56","v57");
  return make_int4(r0, r1, r2, r3);
}

// ---------------------------------------------------------------- init
__global__ void fplstm_init(int* rep) {   // zero hrep+arep (epoch 0 = t=0 h)
  const int tid = threadIdx.x;
  const int n = 2 * RCOPY * NBLK * 16;
  for (int i = tid; i < n; i += 256) rep[i] = 0;
}

// ---------------------------------------------------------------- GEMM
// C(8192x10240) = A(8192x2048) @ W(10240x2048)^T + bx ; write bf16,
// packed layout: xg[t][blk=el>>3][g][el&7], 40 ushorts per (t,blk).
__global__ __launch_bounds__(256, 2) void fplstm_gemm(
    const float* __restrict__ A, const float* __restrict__ W,
    const float* __restrict__ bx, unsigned short* __restrict__ xg)
{
  __shared__ float As[16][132];
  __shared__ float Bs[16][144];
  const int tid = threadIdx.x;
  const int bn = blockIdx.x;      // 80 N-tiles
  const int bm = blockIdx.y;      // 64 M-tiles
  const int tx = tid & 15, ty = tid >> 4;
  const int lrow = tid >> 1;
  const int kh   = (tid & 1) * 8;
  const float* Ap = A + (size_t)(bm * 128 + lrow) * 2048 + kh;
  const float* Wp = W + (size_t)(bn * 128 + lrow) * 2048 + kh;
  const int bmap = lrow + 4 * (lrow >> 5);
  const int bb   = 8 * tx + 4 * (tx >> 2);

  float acc[8][8];
#pragma unroll
  for (int i = 0; i < 8; ++i)
#pragma unroll
    for (int j = 0; j < 8; ++j) acc[i][j] = 0.0f;

  for (int k0 = 0; k0 < 2048; k0 += 16) {
    float4 a0 = *(const float4*)(Ap + k0);
    float4 a1 = *(const float4*)(Ap + k0 + 4);
    float4 b0 = *(const float4*)(Wp + k0);
    float4 b1 = *(const float4*)(Wp + k0 + 4);
    __syncthreads();
    As[kh+0][lrow] = a0.x; As[kh+1][lrow] = a0.y; As[kh+2][lrow] = a0.z; As[kh+3][lrow] = a0.w;
    As[kh+4][lrow] = a1.x; As[kh+5][lrow] = a1.y; As[kh+6][lrow] = a1.z; As[kh+7][lrow] = a1.w;
    Bs[kh+0][bmap] = b0.x; Bs[kh+1][bmap] = b0.y; Bs[kh+2][bmap] = b0.z; Bs[kh+3][bmap] = b0.w;
    Bs[kh+4][bmap] = b1.x; Bs[kh+5][bmap] = b1.y; Bs[kh+6][bmap] = b1.z; Bs[kh+7][bmap] = b1.w;
    __syncthreads();
#pragma unroll
    for (int k = 0; k < 16; ++k) {
      float4 x0 = *(const float4*)(&As[k][8 * ty]);
      float4 x1 = *(const float4*)(&As[k][8 * ty + 4]);
      float4 y0 = *(const float4*)(&Bs[k][bb]);
      float4 y1 = *(const float4*)(&Bs[k][bb + 4]);
      float xa[8] = {x0.x, x0.y, x0.z, x0.w, x1.x, x1.y, x1.z, x1.w};
      float yb[8] = {y0.x, y0.y, y0.z, y0.w, y1.x, y1.y, y1.z, y1.w};
#pragma unroll
      for (int i = 0; i < 8; ++i)
#pragma unroll
        for (int j = 0; j < 8; ++j)
          acc[i][j] = fmaf(xa[i], yb[j], acc[i][j]);
    }
  }

  float bxa[8];
  {
    float4 q0 = *(const float4*)(bx + bn * 128 + 8 * tx);
    float4 q1 = *(const float4*)(bx + bn * 128 + 8 * tx + 4);
    bxa[0]=q0.x; bxa[1]=q0.y; bxa[2]=q0.z; bxa[3]=q0.w;
    bxa[4]=q1.x; bxa[5]=q1.y; bxa[6]=q1.z; bxa[7]=q1.w;
  }
  // packed output offset for this thread's 8-consecutive n5 run
  const int n5 = bn * 128 + 8 * tx;          // aligned 8, never crosses gate
  const int g  = n5 >> 11;
  const int el = n5 & 2047;
  const size_t po = (size_t)(el >> 3) * 40 + g * 8;
#pragma unroll
  for (int i = 0; i < 8; ++i) {
    const size_t row = (size_t)(bm * 128 + 8 * ty + i);
    unsigned short t8[8];
#pragma unroll
    for (int j = 0; j < 8; ++j) t8[j] = f2bf(acc[i][j] + bxa[j]);
    unsigned short* p = xg + row * NG5 + po;
    *(ushort4*)(p)     = make_ushort4(t8[0], t8[1], t8[2], t8[3]);
    *(ushort4*)(p + 4) = make_ushort4(t8[4], t8[5], t8[6], t8[7]);
  }
}

// ---------------------------------------------------------------- recurrence
// Block b owns elements [8b,8b+8). Wave w: gate rg=w&3, half hf=w>>2.
// Operand columns per lane: {1024*hf + 256*k + 4*lane + m} read from LDS.
__global__ __launch_bounds__(NTHR, 2) void fplstm_recur(
    const unsigned short* __restrict__ xg,
    float* hrep, float* arep,
    const float* __restrict__ Wh, const float* __restrict__ bh,
    const float* __restrict__ Wm, const float* __restrict__ bm,
    float* __restrict__ out)
{
  const int tid  = threadIdx.x;
  const int b    = blockIdx.x;
  const int w    = tid >> 6;
  const int lane = tid & 63;
  const int rg   = w & 3;
  const int hf   = w >> 2;
  const int colbase = 1024 * hf + 4 * lane;

  // ---- one-time: weights -> registers ----
  float whr[8][16];
#pragma unroll
  for (int r = 0; r < 8; ++r) {
    const float* wp = Wh + (size_t)(rg * MEM + 8 * b + r) * MEM + colbase;
#pragma unroll
    for (int k = 0; k < 4; ++k) {
      float4 v = *(const float4*)(wp + 256 * k);
      whr[r][4*k+0] = v.x; whr[r][4*k+1] = v.y; whr[r][4*k+2] = v.z; whr[r][4*k+3] = v.w;
    }
  }
  float wmr[2][16];
#pragma unroll
  for (int r = 0; r < 2; ++r) {
    const float* wp = Wm + (size_t)(8 * b + 2 * rg + r) * MEM + colbase;
#pragma unroll
    for (int k = 0; k < 4; ++k) {
      float4 v = *(const float4*)(wp + 256 * k);
      wmr[r][4*k+0] = v.x; wmr[r][4*k+1] = v.y; wmr[r][4*k+2] = v.z; wmr[r][4*k+3] = v.w;
    }
  }

  float bhv0 = 0, bhv1 = 0, bhv2 = 0, bhv3 = 0, bmv = 0;
  if (tid < 8) {
    bhv0 = bh[0 * MEM + 8 * b + tid];
    bhv1 = bh[1 * MEM + 8 * b + tid];
    bhv2 = bh[2 * MEM + 8 * b + tid];
    bhv3 = bh[3 * MEM + 8 * b + tid];
    bmv  = bm[8 * b + tid];
  }

  __shared__ float hs[MEM];         // staged h (phase A) / a (phase B)
  __shared__ float redL[8][8];
  __shared__ float ghL[32];
  __shared__ float redM[8][2];

  // collector addressing: wave w covers lines [32w,32w+32) of copy b&7;
  // lane covers line = 32w + (lane>>1), half = lane&1 (16B of 32B data).
  const int copy  = b & 7;
  const int line  = 32 * w + (lane >> 1);
  const int half  = lane & 1;
  const float* hl = hrep + (size_t)(copy * NBLK + line) * 16 + 4 * half;
  const float* al = arep + (size_t)(copy * NBLK + line) * 16 + 4 * half;

  // publisher addressing (wave 0): lane -> copy lane>>3, elem lane&7.
  int* a_dst = (int*)arep + ((size_t)((lane >> 3) * NBLK + b) * 16 + (lane & 7));
  int* h_dst = (int*)hrep + ((size_t)((lane >> 3) * NBLK + b) * 16 + (lane & 7));

  float c_e = 0.0f, h_last = 0.0f;

  for (int t = 0; t < T_STEPS; ++t) {
    // prefetch xg row t (packed: 40 ushorts at t*NG5 + 40*b; <=2 lines)
    float xv0 = 0, xv1 = 0, xv2 = 0, xv3 = 0, xv4 = 0;
    if (tid < 8) {
      const unsigned short* xp = xg + (size_t)t * NG5 + 40 * b + tid;
      xv0 = bf2f(xp[0]);
      xv1 = bf2f(xp[8]);
      xv2 = bf2f(xp[16]);
      xv3 = bf2f(xp[24]);
      xv4 = bf2f(xp[32]);
    }

    // ---- phase A: poll h lines (every dword's low2 == (2t)&3), stage ----
    {
      int4 v = poll_quad(hl, (2 * t) & 3);
      *(int4*)&hs[8 * line + 4 * half] = v;
    }
    __syncthreads();

    // ---- Wh@h partials ----
    float hreg[16];
#pragma unroll
    for (int k = 0; k < 4; ++k) {
      float4 v = *(const float4*)&hs[colbase + 256 * k];
      hreg[4*k+0] = v.x; hreg[4*k+1] = v.y; hreg[4*k+2] = v.z; hreg[4*k+3] = v.w;
    }
    float acc[8];
#pragma unroll
    for (int r = 0; r < 8; ++r) {
      float s = 0.0f;
#pragma unroll
      for (int j = 0; j < 16; ++j) s = fmaf(whr[r][j], hreg[j], s);
      acc[r] = s;
    }
    // butterfly reduce-scatter
    float v4[4];
    {
      const int b0 = lane & 1;
#pragma unroll
      for (int i = 0; i < 4; ++i) {
        float sent = b0 ? acc[i] : acc[4 + i];
        float got  = __shfl_xor(sent, 1, 64);
        v4[i] = (b0 ? acc[4 + i] : acc[i]) + got;
      }
    }
    float v2[2];
    {
      const int b1 = (lane >> 1) & 1;
#pragma unroll
      for (int i = 0; i < 2; ++i) {
        float sent = b1 ? v4[i] : v4[2 + i];
        float got  = __shfl_xor(sent, 2, 64);
        v2[i] = (b1 ? v4[2 + i] : v4[i]) + got;
      }
    }
    float v1r;
    {
      const int b2 = (lane >> 2) & 1;
      float sent = b2 ? v2[0] : v2[1];
      float got  = __shfl_xor(sent, 4, 64);
      v1r = (b2 ? v2[1] : v2[0]) + got;
    }
    v1r += __shfl_xor(v1r, 8, 64);
    v1r += __shfl_xor(v1r, 16, 64);
    v1r += __shfl_xor(v1r, 32, 64);
    if (lane < 8) {
      const int r = 4 * (lane & 1) + 2 * ((lane >> 1) & 1) + ((lane >> 2) & 1);
      redL[w][r] = v1r;
    }
    __syncthreads();

    // ---- wave 0: gates, publish a (8 copies, epoch-tagged dwords) ----
    float g_i = 0, g_o = 0, g_fc = 0, a_e = 0;
    if (w == 0) {
      if (tid < 32)
        ghL[tid] = redL[tid >> 3][tid & 7] + redL[(tid >> 3) + 4][tid & 7];
      if (tid < 8) {
        float gi = sigmoidf_(xv0 + ghL[tid]      + bhv0);
        float go = sigmoidf_(xv1 + ghL[8 + tid]  + bhv1);
        float gz = sigmoidf_(xv2 + ghL[16 + tid] + bhv2);
        float gf = sigmoidf_(xv3 + ghL[24 + tid] + bhv3);
        a_e = gz * tanhf_(c_e);
        g_i = gi; g_o = go; g_fc = gf * c_e;
      }
      float av = __shfl(a_e, lane & 7, 64);
      store_i_cc(a_dst, (__float_as_int(av) & ~3) | (int)((2 * t + 1) & 3));
    }

    // ---- phase B: poll a lines (low2 == (2t+1)&3), stage to LDS ----
    // (hs reuse safe: all hreg ds_reads precede the redL barrier)
    {
      int4 v = poll_quad(al, (2 * t + 1) & 3);
      *(int4*)&hs[8 * line + 4 * half] = v;
    }
    __syncthreads();

    // ---- Wm@a partials ----
    float areg[16];
#pragma unroll
    for (int k = 0; k < 4; ++k) {
      float4 v = *(const float4*)&hs[colbase + 256 * k];
      areg[4*k+0] = v.x; areg[4*k+1] = v.y; areg[4*k+2] = v.z; areg[4*k+3] = v.w;
    }
    float am0 = 0.0f, am1 = 0.0f;
#pragma unroll
    for (int j = 0; j < 16; ++j) am0 = fmaf(wmr[0][j], areg[j], am0);
#pragma unroll
    for (int j = 0; j < 16; ++j) am1 = fmaf(wmr[1][j], areg[j], am1);
    {
      float sent = (lane & 1) ? am0 : am1;
      float got  = __shfl_xor(sent, 1, 64);
      float vv = ((lane & 1) ? am1 : am0) + got;
      vv += __shfl_xor(vv, 2, 64);
      vv += __shfl_xor(vv, 4, 64);
      vv += __shfl_xor(vv, 8, 64);
      vv += __shfl_xor(vv, 16, 64);
      vv += __shfl_xor(vv, 32, 64);
      if (lane < 2) redM[w][lane] = vv;
    }
    __syncthreads();

    // ---- wave 0: c/h update, publish h (8 copies, epoch-tagged) ----
    if (w == 0) {
      if (tid < 8) {
        float mg = redM[tid >> 1][tid & 1] + redM[(tid >> 1) + 4][tid & 1];
        float u  = tanhf_(xv4 + mg + bmv);
        c_e    = fmaf(g_i, u, g_fc);
        h_last = g_o * tanhf_(c_e);
      }
      float hv = __shfl(h_last, lane & 7, 64);
      store_i_cc(h_dst, (__float_as_int(hv) & ~3) | (int)((2 * t + 2) & 3));
    }
    // next iteration's phase-A poll (epoch (2t+2)&3) is the barrier
  }

  if (tid < 8) out[8 * b + tid] = h_last;
}

// ---------------------------------------------------------------- launch
extern "C" void kernel_launch(void* const* d_in, const int* in_sizes, int n_in,
                              void* d_out, int out_size, void* d_ws, size_t ws_size,
                              hipStream_t stream) {
  const float* inputs = (const float*)d_in[0];
  const float* Wx     = (const float*)d_in[1];
  const float* bx     = (const float*)d_in[2];
  const float* Wh     = (const float*)d_in[3];
  const float* bh     = (const float*)d_in[4];
  const float* Wm     = (const float*)d_in[5];
  const float* bm     = (const float*)d_in[6];
  float* out = (float*)d_out;
  char* ws = (char*)d_ws;

  if (ws_size < WS_NEEDED) {
    fprintf(stderr, "FPLSTM: ws_size %zu < needed %zu -- cannot run\n",
            ws_size, (size_t)WS_NEEDED);
    return;
  }

  unsigned short* xg = (unsigned short*)ws;
  float* hrep = (float*)(ws + HREP_OFF);
  float* arep = (float*)(ws + AREP_OFF);

  fplstm_init<<<1, 256, 0, stream>>>((int*)hrep);
  fplstm_gemm<<<dim3(80, 64), 256, 0, stream>>>(inputs, Wx, bx, xg);

  void* args[] = {(void*)&xg, (void*)&hrep, (void*)&arep,
                  (void*)&Wh, (void*)&bh, (void*)&Wm, (void*)&bm, (void*)&out};
  hipError_t e = hipLaunchCooperativeKernel((void*)fplstm_recur, dim3(NBLK),
                                            dim3(NTHR), args, 0, stream);
  if (e != hipSuccess) {
    fprintf(stderr, "FPLSTM: coop launch failed (%d), plain launch\n", (int)e);
    fplstm_recur<<<dim3(NBLK), dim3(NTHR), 0, stream>>>(
        xg, hrep, arep, Wh, bh, Wm, bm, out);
  }
}

// Round 8
// 42297.079 us; speedup vs baseline: 1.3107x; 1.1599x over previous
//
#include <hip/hip_runtime.h>
#include <cstdio>
#include <cstdint>
#include <cstddef>

// FPLSTM: T=8192 steps, IN=2048, M=2048.
//  Kernel 1: init  (zero replicated h/a exchange arrays)
//  Kernel 2: gemm  xg[t,n] = inputs[t,:]·Wx[n,:] + bx[n], stored bf16 PACKED
//            per-block: xg[t][blk][gate][8] so one block's 40 ushorts/step
//            sit in <=2 cache lines (was 5 lines across 10KB).
//  Kernel 3: persistent cooperative recurrence, 256 blocks x 512 thr.
//
// R11 = R10 resubmitted unchanged (R10 bench died to a broker-level
// container failure before compile/run; kernel re-audited: coverage
// bijective, no deadlock path, shared-line writes dword-disjoint).
//
// R10 = R4 structure (proven 38.6ms recurrence) + packed xg (verified
// R9) + DENSE exchange arrays:
//  - poll: single-slot load+vmcnt(0) in ONE asm block (R4-proven).
//    R9's depth-2 poll was net-negative: the exit vmcnt(0) drain of the
//    speculative in-flight slot (~tau/2) cancels the sampling gain
//    (~tau/4) and the doubled poll traffic inflates tau via congestion
//    (43.6ms vs 38.6ms measured).
//  - hrep/arep dense (NO pad): copy stride 8KB, block offset 32B.
//    A wave's poll is now 1KB fully contiguous (lane addr = base +
//    16B*lane) -> 16 full-line requests/wave instead of 32 strided 32B
//    sector reads. Halves the fabric request rate of the dominant
//    traffic (poll rounds). Writers: two adjacent blocks write
//    disjoint 32B halves of one line (dword-disjoint, no RMW hazard).
//
// Epoch scheme (R4): every published dword carries epoch in its low 2
// mantissa bits (error <= 4e-7 rel). h line epoch (2t+2)&3 at end of
// step t; a line epoch (2t+1)&3 in phase B of step t. Lap argument: a
// writer's next publish transitively requires all blocks' prior-phase
// publishes, which require consumption -> staleness bounded to one
// epoch; adjacent epochs of a block's slot differ by 2 mod 4 (no
// alias). Init zeros = epoch 0 = the t=0 h.

#define T_STEPS 8192
#define MEM     2048
#define NG5     10240   // 5*MEM
#define NBLK    256
#define NTHR    512
#define RCOPY   8

static constexpr size_t XG_BYTES  = (size_t)T_STEPS * NG5 * 2;     // bf16 xg
static constexpr size_t HREP_OFF  = XG_BYTES;
static constexpr size_t REP_BYTES = (size_t)RCOPY * NBLK * 32;     // dense: 8 floats/block
static constexpr size_t AREP_OFF  = HREP_OFF + REP_BYTES;
static constexpr size_t WS_NEEDED = AREP_OFF + REP_BYTES;

__device__ __forceinline__ float bf2f(unsigned short u) {
  return __uint_as_float(((unsigned int)u) << 16);
}
__device__ __forceinline__ unsigned short f2bf(float f) {
  unsigned int u = __float_as_uint(f);
  u += 0x7FFFu + ((u >> 16) & 1u);   // RNE; inputs finite
  return (unsigned short)(u >> 16);
}
__device__ __forceinline__ float sigmoidf_(float x) {
  return 1.0f / (1.0f + __expf(-x));
}
__device__ __forceinline__ float tanhf_(float x) {
  x = fminf(fmaxf(x, -15.0f), 15.0f);
  float e = __expf(2.0f * x);
  return (e - 1.0f) / (e + 1.0f);
}

// ---- per-access coherent ops (bypass L1+L2; coherence point = L3) ----
__device__ __forceinline__ void store_i_cc(int* p, int v) {
  asm volatile("global_store_dword %0, %1, off sc0 sc1"
               :: "v"(p), "v"(v) : "memory");
}
// single-block load+wait: no in-flight state escapes the asm block.
__device__ __forceinline__ int4 load4_cc(const float* p) {
  int4 v;
  asm volatile("global_load_dwordx4 %0, %1, off sc0 sc1\n\t"
               "s_waitcnt vmcnt(0)"
               : "=v"(v) : "v"(p) : "memory");
  return v;
}
__device__ __forceinline__ bool quad_ok(const int4 v, const int e2) {
  return ((((v.x ^ e2) | (v.y ^ e2) | (v.z ^ e2) | (v.w ^ e2)) & 3) == 0);
}
__device__ __forceinline__ int4 poll_quad(const float* p, const int e2) {
  for (;;) {
    int4 v = load4_cc(p);
    if (__all(quad_ok(v, e2))) return v;
  }
}

// ---------------------------------------------------------------- init
__global__ void fplstm_init(int* rep) {   // zero hrep+arep (epoch 0 = t=0 h)
  const int tid = threadIdx.x;
  const int n = 2 * RCOPY * NBLK * 8;
  for (int i = tid; i < n; i += 256) rep[i] = 0;
}

// ---------------------------------------------------------------- GEMM
// C(8192x10240) = A(8192x2048) @ W(10240x2048)^T + bx ; write bf16,
// packed layout: xg[t][blk=el>>3][g][el&7], 40 ushorts per (t,blk).
__global__ __launch_bounds__(256, 2) void fplstm_gemm(
    const float* __restrict__ A, const float* __restrict__ W,
    const float* __restrict__ bx, unsigned short* __restrict__ xg)
{
  __shared__ float As[16][132];
  __shared__ float Bs[16][144];
  const int tid = threadIdx.x;
  const int bn = blockIdx.x;      // 80 N-tiles
  const int bm = blockIdx.y;      // 64 M-tiles
  const int tx = tid & 15, ty = tid >> 4;
  const int lrow = tid >> 1;
  const int kh   = (tid & 1) * 8;
  const float* Ap = A + (size_t)(bm * 128 + lrow) * 2048 + kh;
  const float* Wp = W + (size_t)(bn * 128 + lrow) * 2048 + kh;
  const int bmap = lrow + 4 * (lrow >> 5);
  const int bb   = 8 * tx + 4 * (tx >> 2);

  float acc[8][8];
#pragma unroll
  for (int i = 0; i < 8; ++i)
#pragma unroll
    for (int j = 0; j < 8; ++j) acc[i][j] = 0.0f;

  for (int k0 = 0; k0 < 2048; k0 += 16) {
    float4 a0 = *(const float4*)(Ap + k0);
    float4 a1 = *(const float4*)(Ap + k0 + 4);
    float4 b0 = *(const float4*)(Wp + k0);
    float4 b1 = *(const float4*)(Wp + k0 + 4);
    __syncthreads();
    As[kh+0][lrow] = a0.x; As[kh+1][lrow] = a0.y; As[kh+2][lrow] = a0.z; As[kh+3][lrow] = a0.w;
    As[kh+4][lrow] = a1.x; As[kh+5][lrow] = a1.y; As[kh+6][lrow] = a1.z; As[kh+7][lrow] = a1.w;
    Bs[kh+0][bmap] = b0.x; Bs[kh+1][bmap] = b0.y; Bs[kh+2][bmap] = b0.z; Bs[kh+3][bmap] = b0.w;
    Bs[kh+4][bmap] = b1.x; Bs[kh+5][bmap] = b1.y; Bs[kh+6][bmap] = b1.z; Bs[kh+7][bmap] = b1.w;
    __syncthreads();
#pragma unroll
    for (int k = 0; k < 16; ++k) {
      float4 x0 = *(const float4*)(&As[k][8 * ty]);
      float4 x1 = *(const float4*)(&As[k][8 * ty + 4]);
      float4 y0 = *(const float4*)(&Bs[k][bb]);
      float4 y1 = *(const float4*)(&Bs[k][bb + 4]);
      float xa[8] = {x0.x, x0.y, x0.z, x0.w, x1.x, x1.y, x1.z, x1.w};
      float yb[8] = {y0.x, y0.y, y0.z, y0.w, y1.x, y1.y, y1.z, y1.w};
#pragma unroll
      for (int i = 0; i < 8; ++i)
#pragma unroll
        for (int j = 0; j < 8; ++j)
          acc[i][j] = fmaf(xa[i], yb[j], acc[i][j]);
    }
  }

  float bxa[8];
  {
    float4 q0 = *(const float4*)(bx + bn * 128 + 8 * tx);
    float4 q1 = *(const float4*)(bx + bn * 128 + 8 * tx + 4);
    bxa[0]=q0.x; bxa[1]=q0.y; bxa[2]=q0.z; bxa[3]=q0.w;
    bxa[4]=q1.x; bxa[5]=q1.y; bxa[6]=q1.z; bxa[7]=q1.w;
  }
  // packed output offset for this thread's 8-consecutive n5 run
  const int n5 = bn * 128 + 8 * tx;          // aligned 8, never crosses gate
  const int g  = n5 >> 11;
  const int el = n5 & 2047;
  const size_t po = (size_t)(el >> 3) * 40 + g * 8;
#pragma unroll
  for (int i = 0; i < 8; ++i) {
    const size_t row = (size_t)(bm * 128 + 8 * ty + i);
    unsigned short t8[8];
#pragma unroll
    for (int j = 0; j < 8; ++j) t8[j] = f2bf(acc[i][j] + bxa[j]);
    unsigned short* p = xg + row * NG5 + po;
    *(ushort4*)(p)     = make_ushort4(t8[0], t8[1], t8[2], t8[3]);
    *(ushort4*)(p + 4) = make_ushort4(t8[4], t8[5], t8[6], t8[7]);
  }
}

// ---------------------------------------------------------------- recurrence
// Block b owns elements [8b,8b+8). Wave w: gate rg=w&3, half hf=w>>2.
// Operand columns per lane: {1024*hf + 256*k + 4*lane + m} read from LDS.
__global__ __launch_bounds__(NTHR, 2) void fplstm_recur(
    const unsigned short* __restrict__ xg,
    float* hrep, float* arep,
    const float* __restrict__ Wh, const float* __restrict__ bh,
    const float* __restrict__ Wm, const float* __restrict__ bm,
    float* __restrict__ out)
{
  const int tid  = threadIdx.x;
  const int b    = blockIdx.x;
  const int w    = tid >> 6;
  const int lane = tid & 63;
  const int rg   = w & 3;
  const int hf   = w >> 2;
  const int colbase = 1024 * hf + 4 * lane;

  // ---- one-time: weights -> registers ----
  float whr[8][16];
#pragma unroll
  for (int r = 0; r < 8; ++r) {
    const float* wp = Wh + (size_t)(rg * MEM + 8 * b + r) * MEM + colbase;
#pragma unroll
    for (int k = 0; k < 4; ++k) {
      float4 v = *(const float4*)(wp + 256 * k);
      whr[r][4*k+0] = v.x; whr[r][4*k+1] = v.y; whr[r][4*k+2] = v.z; whr[r][4*k+3] = v.w;
    }
  }
  float wmr[2][16];
#pragma unroll
  for (int r = 0; r < 2; ++r) {
    const float* wp = Wm + (size_t)(8 * b + 2 * rg + r) * MEM + colbase;
#pragma unroll
    for (int k = 0; k < 4; ++k) {
      float4 v = *(const float4*)(wp + 256 * k);
      wmr[r][4*k+0] = v.x; wmr[r][4*k+1] = v.y; wmr[r][4*k+2] = v.z; wmr[r][4*k+3] = v.w;
    }
  }

  float bhv0 = 0, bhv1 = 0, bhv2 = 0, bhv3 = 0, bmv = 0;
  if (tid < 8) {
    bhv0 = bh[0 * MEM + 8 * b + tid];
    bhv1 = bh[1 * MEM + 8 * b + tid];
    bhv2 = bh[2 * MEM + 8 * b + tid];
    bhv3 = bh[3 * MEM + 8 * b + tid];
    bmv  = bm[8 * b + tid];
  }

  __shared__ float hs[MEM];         // staged h (phase A) / a (phase B)
  __shared__ float redL[8][8];
  __shared__ float ghL[32];
  __shared__ float redM[8][2];

  // collector addressing (dense): copy c region = c*2048 dwords; block j's
  // 8 floats at j*8. Wave w covers blocks [32w,32w+32): lane offset =
  // 256*w + 4*lane dwords -> 1KB contiguous per wave, fully coalesced.
  const int copy = b & 7;
  const int soff = 256 * w + 4 * lane;       // dwords, also the LDS offset
  const float* hl = hrep + (size_t)copy * 2048 + soff;
  const float* al = arep + (size_t)copy * 2048 + soff;

  // publisher addressing (wave 0): lane -> copy lane>>3, elem lane&7.
  int* a_dst = (int*)arep + ((size_t)(lane >> 3) * 2048 + b * 8 + (lane & 7));
  int* h_dst = (int*)hrep + ((size_t)(lane >> 3) * 2048 + b * 8 + (lane & 7));

  float c_e = 0.0f, h_last = 0.0f;

  for (int t = 0; t < T_STEPS; ++t) {
    // prefetch xg row t (packed: 40 ushorts at t*NG5 + 40*b; <=2 lines)
    float xv0 = 0, xv1 = 0, xv2 = 0, xv3 = 0, xv4 = 0;
    if (tid < 8) {
      const unsigned short* xp = xg + (size_t)t * NG5 + 40 * b + tid;
      xv0 = bf2f(xp[0]);
      xv1 = bf2f(xp[8]);
      xv2 = bf2f(xp[16]);
      xv3 = bf2f(xp[24]);
      xv4 = bf2f(xp[32]);
    }

    // ---- phase A: poll h quads (every dword's low2 == (2t)&3), stage ----
    {
      int4 v = poll_quad(hl, (2 * t) & 3);
      *(int4*)&hs[soff] = v;
    }
    __syncthreads();

    // ---- Wh@h partials ----
    float hreg[16];
#pragma unroll
    for (int k = 0; k < 4; ++k) {
      float4 v = *(const float4*)&hs[colbase + 256 * k];
      hreg[4*k+0] = v.x; hreg[4*k+1] = v.y; hreg[4*k+2] = v.z; hreg[4*k+3] = v.w;
    }
    float acc[8];
#pragma unroll
    for (int r = 0; r < 8; ++r) {
      float s = 0.0f;
#pragma unroll
      for (int j = 0; j < 16; ++j) s = fmaf(whr[r][j], hreg[j], s);
      acc[r] = s;
    }
    // butterfly reduce-scatter
    float v4[4];
    {
      const int b0 = lane & 1;
#pragma unroll
      for (int i = 0; i < 4; ++i) {
        float sent = b0 ? acc[i] : acc[4 + i];
        float got  = __shfl_xor(sent, 1, 64);
        v4[i] = (b0 ? acc[4 + i] : acc[i]) + got;
      }
    }
    float v2[2];
    {
      const int b1 = (lane >> 1) & 1;
#pragma unroll
      for (int i = 0; i < 2; ++i) {
        float sent = b1 ? v4[i] : v4[2 + i];
        float got  = __shfl_xor(sent, 2, 64);
        v2[i] = (b1 ? v4[2 + i] : v4[i]) + got;
      }
    }
    float v1r;
    {
      const int b2 = (lane >> 2) & 1;
      float sent = b2 ? v2[0] : v2[1];
      float got  = __shfl_xor(sent, 4, 64);
      v1r = (b2 ? v2[1] : v2[0]) + got;
    }
    v1r += __shfl_xor(v1r, 8, 64);
    v1r += __shfl_xor(v1r, 16, 64);
    v1r += __shfl_xor(v1r, 32, 64);
    if (lane < 8) {
      const int r = 4 * (lane & 1) + 2 * ((lane >> 1) & 1) + ((lane >> 2) & 1);
      redL[w][r] = v1r;
    }
    __syncthreads();

    // ---- wave 0: gates, publish a (8 copies, epoch-tagged dwords) ----
    float g_i = 0, g_o = 0, g_fc = 0, a_e = 0;
    if (w == 0) {
      if (tid < 32)
        ghL[tid] = redL[tid >> 3][tid & 7] + redL[(tid >> 3) + 4][tid & 7];
      if (tid < 8) {
        float gi = sigmoidf_(xv0 + ghL[tid]      + bhv0);
        float go = sigmoidf_(xv1 + ghL[8 + tid]  + bhv1);
        float gz = sigmoidf_(xv2 + ghL[16 + tid] + bhv2);
        float gf = sigmoidf_(xv3 + ghL[24 + tid] + bhv3);
        a_e = gz * tanhf_(c_e);
        g_i = gi; g_o = go; g_fc = gf * c_e;
      }
      float av = __shfl(a_e, lane & 7, 64);
      store_i_cc(a_dst, (__float_as_int(av) & ~3) | (int)((2 * t + 1) & 3));
    }

    // ---- phase B: poll a quads (low2 == (2t+1)&3), stage to LDS ----
    // (hs reuse safe: all hreg ds_reads precede the redL barrier)
    {
      int4 v = poll_quad(al, (2 * t + 1) & 3);
      *(int4*)&hs[soff] = v;
    }
    __syncthreads();

    // ---- Wm@a partials ----
    float areg[16];
#pragma unroll
    for (int k = 0; k < 4; ++k) {
      float4 v = *(const float4*)&hs[colbase + 256 * k];
      areg[4*k+0] = v.x; areg[4*k+1] = v.y; areg[4*k+2] = v.z; areg[4*k+3] = v.w;
    }
    float am0 = 0.0f, am1 = 0.0f;
#pragma unroll
    for (int j = 0; j < 16; ++j) am0 = fmaf(wmr[0][j], areg[j], am0);
#pragma unroll
    for (int j = 0; j < 16; ++j) am1 = fmaf(wmr[1][j], areg[j], am1);
    {
      float sent = (lane & 1) ? am0 : am1;
      float got  = __shfl_xor(sent, 1, 64);
      float vv = ((lane & 1) ? am1 : am0) + got;
      vv += __shfl_xor(vv, 2, 64);
      vv += __shfl_xor(vv, 4, 64);
      vv += __shfl_xor(vv, 8, 64);
      vv += __shfl_xor(vv, 16, 64);
      vv += __shfl_xor(vv, 32, 64);
      if (lane < 2) redM[w][lane] = vv;
    }
    __syncthreads();

    // ---- wave 0: c/h update, publish h (8 copies, epoch-tagged) ----
    if (w == 0) {
      if (tid < 8) {
        float mg = redM[tid >> 1][tid & 1] + redM[(tid >> 1) + 4][tid & 1];
        float u  = tanhf_(xv4 + mg + bmv);
        c_e    = fmaf(g_i, u, g_fc);
        h_last = g_o * tanhf_(c_e);
      }
      float hv = __shfl(h_last, lane & 7, 64);
      store_i_cc(h_dst, (__float_as_int(hv) & ~3) | (int)((2 * t + 2) & 3));
    }
    // next iteration's phase-A poll (epoch (2t+2)&3) is the barrier
  }

  if (tid < 8) out[8 * b + tid] = h_last;
}

// ---------------------------------------------------------------- launch
extern "C" void kernel_launch(void* const* d_in, const int* in_sizes, int n_in,
                              void* d_out, int out_size, void* d_ws, size_t ws_size,
                              hipStream_t stream) {
  const float* inputs = (const float*)d_in[0];
  const float* Wx     = (const float*)d_in[1];
  const float* bx     = (const float*)d_in[2];
  const float* Wh     = (const float*)d_in[3];
  const float* bh     = (const float*)d_in[4];
  const float* Wm     = (const float*)d_in[5];
  const float* bm     = (const float*)d_in[6];
  float* out = (float*)d_out;
  char* ws = (char*)d_ws;

  if (ws_size < WS_NEEDED) {
    fprintf(stderr, "FPLSTM: ws_size %zu < needed %zu -- cannot run\n",
            ws_size, (size_t)WS_NEEDED);
    return;
  }

  unsigned short* xg = (unsigned short*)ws;
  float* hrep = (float*)(ws + HREP_OFF);
  float* arep = (float*)(ws + AREP_OFF);

  fplstm_init<<<1, 256, 0, stream>>>((int*)hrep);
  fplstm_gemm<<<dim3(80, 64), 256, 0, stream>>>(inputs, Wx, bx, xg);

  void* args[] = {(void*)&xg, (void*)&hrep, (void*)&arep,
                  (void*)&Wh, (void*)&bh, (void*)&Wm, (void*)&bm, (void*)&out};
  hipError_t e = hipLaunchCooperativeKernel((void*)fplstm_recur, dim3(NBLK),
                                            dim3(NTHR), args, 0, stream);
  if (e != hipSuccess) {
    fprintf(stderr, "FPLSTM: coop launch failed (%d), plain launch\n", (int)e);
    fplstm_recur<<<dim3(NBLK), dim3(NTHR), 0, stream>>>(
        xg, hrep, arep, Wh, bh, Wm, bm, out);
  }
}